// Round 16
// baseline (430.903 us; speedup 1.0000x reference)
//
#include <hip/hip_runtime.h>
#include <hip/hip_fp16.h>

#define N0 50000
#define N1 100000
#define N2 25000
#define E00 200000
#define E11 200000
#define E10 100000
#define E21 50000
#define EE  550000   // E00+E10+E11+E21 (concatenated edge space)
#define ND  300000   // 50000(u00)+50000(b10)+100000(u11)+100000(b21) dst slots
#define NB  293      // ceil(ND/1024) scan blocks
#define NT_ALL 18750 // ND/16 semantic tiles
#define HID 128
#define INC 64

typedef _Float16 half8 __attribute__((ext_vector_type(8)));
typedef _Float16 half4_t __attribute__((ext_vector_type(4)));
typedef float float4v __attribute__((ext_vector_type(4)));
typedef float floatx2 __attribute__((ext_vector_type(2)));

// ---------------------------------------------------------------------------
// Kernel A: prep (+count fused, independent work co-runs).
// ---------------------------------------------------------------------------
struct PrepT {
    const float* W; const float* bias;
    const float* av0; const float* av1; const float* av2; const float* av3;
    _Float16* wtg; _Float16* adtg; float* bdc;
};

__device__ __forceinline__ void decode_edge(
    int e, const int* ei00, const int* ei10, const int* ei11, const int* ei21,
    int& src, int& slot)
{
    if (e < E00)                    { src = ei00[e];               slot = ei00[E00 + e]; }
    else if (e < E00 + E10)         { int i = e - E00;             src = ei10[i]; slot = 50000  + ei10[E10 + i]; }
    else if (e < E00 + E10 + E11)   { int i = e - E00 - E10;       src = ei11[i]; slot = 100000 + ei11[E11 + i]; }
    else                            { int i = e - E00 - E10 - E11; src = ei21[i]; slot = 200000 + ei21[E21 + i]; }
}

__global__ __launch_bounds__(256) void prep_kernel(
    PrepT p0, PrepT p1, PrepT p2,
    const float* __restrict__ kw, const float* __restrict__ lw,
    unsigned char* __restrict__ kwf8,
    const int* __restrict__ ei00, const int* __restrict__ ei10,
    const int* __restrict__ ei11, const int* __restrict__ ei21,
    int* __restrict__ cnt)
{
    if (blockIdx.x >= 32) {
        int e = (blockIdx.x - 32) * 256 + threadIdx.x;
        if (e >= EE) return;
        int src, slot;
        decode_edge(e, ei00, ei10, ei11, ei21, src, slot);
        atomicAdd(&cnt[slot], 1);
        return;
    }
    if (blockIdx.x >= 24) {
        int base = (blockIdx.x - 24) * 256 + threadIdx.x;
        for (int it = 0; it < 9; ++it) {
            int idx = base + it * 2048;
            int f = idx >> 7, g = idx & 127;
            float v;
            if (f < 128)      v = kw[g * 128 + f];
            else if (f < 130) v = lw[g * 2 + (f - 128)];
            else              v = 0.f;
            int r = __builtin_amdgcn_cvt_pk_fp8_f32(v, 0.f, 0, false);
            kwf8[idx] = (unsigned char)r;
        }
        return;
    }
    PrepT P = (blockIdx.x >= 16) ? p2 : (blockIdx.x >= 8) ? p1 : p0;
    const int lb = blockIdx.x & 7;
    const int t2 = lb * 256 + threadIdx.x;   // 0..2047
    {
        int f = t2 >> 4, g0 = (t2 & 15) * 4;
        half4_t v;
#pragma unroll
        for (int j = 0; j < 4; ++j) v[j] = (_Float16)P.W[(g0 + j) * 128 + f];
        *(half4_t*)&P.wtg[f * 64 + g0] = v;
    }
    {
        int c = t2 >> 6, g = t2 & 63;
        const float* av = (c < 8) ? P.av0 : (c < 16) ? P.av1 : (c < 24) ? P.av2 : P.av3;
        float v = 0.f;
        if (av) {
            int hh = c & 7;
#pragma unroll
            for (int d = 0; d < 16; ++d)
                v += P.W[g * 128 + hh * 16 + d] * av[hh * 16 + d];
        }
        P.adtg[c * 64 + g] = (_Float16)v;
    }
    if (lb == 0 && threadIdx.x < 32) {
        int c = threadIdx.x;
        const float* av = (c < 8) ? P.av0 : (c < 16) ? P.av1 : (c < 24) ? P.av2 : P.av3;
        float v = 0.f;
        if (av) {
            int hh = c & 7;
#pragma unroll
            for (int d = 0; d < 16; ++d)
                v += P.bias[hh * 16 + d] * av[hh * 16 + d];
        }
        P.bdc[c] = v;
    }
}

// ---------------------------------------------------------------------------
// Kernel B: proj_mfma (+scan1 fused). h = x @ W + b (fp8 e4m3) + attn dots.
// ---------------------------------------------------------------------------
struct PT {
    const float* x; const float* bias; unsigned char* h;
    float* ao0; float* ao1; float* ao2; float* ao3;
    const _Float16* wtg; const _Float16* adtg; const float* bdc;
    int N; int ntiles; int bstart; int nblocks;
};

#define HPAD 136  // halves; row stride 272 B (16B-aligned b128 reads)
#define PROJ_BLKS 1024

__global__ __launch_bounds__(256, 2) void proj_mfma(
    PT t0, PT t1, PT t2,
    const int* __restrict__ cnt, int* __restrict__ part)
{
    __shared__ _Float16 ht[4][16][HPAD];   // 17.4 KB: per-wave h tile (f16)
    __shared__ int swt[4];
    const int tid = threadIdx.x;
    const int lane = tid & 63, wv = tid >> 6;
    const int fi = lane & 15, hi = lane >> 4;

    if (blockIdx.x >= PROJ_BLKS) {
        const int b = blockIdx.x - PROJ_BLKS;
        int i0 = b * 1024 + tid * 4;
        int s = 0;
#pragma unroll
        for (int k = 0; k < 4; ++k) { int i = i0 + k; s += (i < ND) ? cnt[i] : 0; }
#pragma unroll
        for (int off = 1; off < 64; off <<= 1) s += __shfl_xor(s, off);
        if ((tid & 63) == 0) swt[tid >> 6] = s;
        __syncthreads();
        if (tid == 0) part[b] = swt[0] + swt[1] + swt[2] + swt[3];
        return;
    }

    PT A = (blockIdx.x >= t2.bstart) ? t2 : (blockIdx.x >= t1.bstart) ? t1 : t0;

    half8 bfr[8][2], bd[2][2];
#pragma unroll
    for (int nt = 0; nt < 8; ++nt)
#pragma unroll
        for (int kb = 0; kb < 2; ++kb)
            bfr[nt][kb] = *(const half8*)&A.wtg[(nt * 16 + fi) * 64 + kb * 32 + hi * 8];
#pragma unroll
    for (int t = 0; t < 2; ++t)
#pragma unroll
        for (int kb = 0; kb < 2; ++kb)
            bd[t][kb] = *(const half8*)&A.adtg[(t * 16 + fi) * 64 + kb * 32 + hi * 8];

    float bvv[8];
#pragma unroll
    for (int nt = 0; nt < 8; ++nt) bvv[nt] = A.bias[nt * 16 + fi];
    const float bdc0 = A.bdc[fi];
    const float bdc1 = A.bdc[16 + fi];

    float* aolo = (fi >= 8) ? A.ao1 : A.ao0;
    float* aohi = (fi >= 8) ? A.ao3 : A.ao2;
    const bool has_hi = (A.ao2 != nullptr) || (A.ao3 != nullptr);

    const int stride = A.nblocks * 4;
    for (int t = (blockIdx.x - A.bstart) * 4 + wv; t < A.ntiles; t += stride) {
        const int base = t * 16;
        int rsrc = base + fi; if (rsrc >= A.N) rsrc = A.N - 1;
        const float* xp = A.x + (size_t)rsrc * 64 + hi * 8;
        float4 u0 = *(const float4*)(xp);
        float4 u1 = *(const float4*)(xp + 4);
        float4 u2 = *(const float4*)(xp + 32);
        float4 u3 = *(const float4*)(xp + 36);
        half8 a0, a1;
        a0[0] = (_Float16)u0.x; a0[1] = (_Float16)u0.y; a0[2] = (_Float16)u0.z; a0[3] = (_Float16)u0.w;
        a0[4] = (_Float16)u1.x; a0[5] = (_Float16)u1.y; a0[6] = (_Float16)u1.z; a0[7] = (_Float16)u1.w;
        a1[0] = (_Float16)u2.x; a1[1] = (_Float16)u2.y; a1[2] = (_Float16)u2.z; a1[3] = (_Float16)u2.w;
        a1[4] = (_Float16)u3.x; a1[5] = (_Float16)u3.y; a1[6] = (_Float16)u3.z; a1[7] = (_Float16)u3.w;

        float4v c[8];
#pragma unroll
        for (int nt = 0; nt < 8; ++nt) {
            float4v z = {0.f, 0.f, 0.f, 0.f};
            z = __builtin_amdgcn_mfma_f32_16x16x32_f16(a0, bfr[nt][0], z, 0, 0, 0);
            z = __builtin_amdgcn_mfma_f32_16x16x32_f16(a1, bfr[nt][1], z, 0, 0, 0);
            c[nt] = z;
        }
        float4v d0 = {0.f, 0.f, 0.f, 0.f};
        d0 = __builtin_amdgcn_mfma_f32_16x16x32_f16(a0, bd[0][0], d0, 0, 0, 0);
        d0 = __builtin_amdgcn_mfma_f32_16x16x32_f16(a1, bd[0][1], d0, 0, 0, 0);
        float4v d1 = {0.f, 0.f, 0.f, 0.f};
        if (has_hi) {
            d1 = __builtin_amdgcn_mfma_f32_16x16x32_f16(a0, bd[1][0], d1, 0, 0, 0);
            d1 = __builtin_amdgcn_mfma_f32_16x16x32_f16(a1, bd[1][1], d1, 0, 0, 0);
        }

#pragma unroll
        for (int nt = 0; nt < 8; ++nt)
#pragma unroll
            for (int r = 0; r < 4; ++r)
                ht[wv][hi * 4 + r][nt * 16 + fi] = (_Float16)(c[nt][r] + bvv[nt]);
#pragma unroll
        for (int i = 0; i < 4; ++i) {
            int row = i * 4 + hi;
            int node = base + row;
            if (node < A.N) {
                half8 v = *(const half8*)&ht[wv][row][fi * 8];
                int pa = __builtin_amdgcn_cvt_pk_fp8_f32((float)v[0], (float)v[1], 0, false);
                pa = __builtin_amdgcn_cvt_pk_fp8_f32((float)v[2], (float)v[3], pa, true);
                int pb = __builtin_amdgcn_cvt_pk_fp8_f32((float)v[4], (float)v[5], 0, false);
                pb = __builtin_amdgcn_cvt_pk_fp8_f32((float)v[6], (float)v[7], pb, true);
                int2 o = {pa, pb};
                *(int2*)(A.h + (size_t)node * 128 + fi * 8) = o;
            }
        }
        if (aolo) {
#pragma unroll
            for (int r = 0; r < 4; ++r) {
                int node = base + hi * 4 + r;
                if (node < A.N) aolo[(size_t)node * 8 + (fi & 7)] = d0[r] + bdc0;
            }
        }
        if (aohi) {
#pragma unroll
            for (int r = 0; r < 4; ++r) {
                int node = base + hi * 4 + r;
                if (node < A.N) aohi[(size_t)node * 8 + (fi & 7)] = d1[r] + bdc1;
            }
        }
    }
}

// ---------------------------------------------------------------------------
// Kernel C: scan23 — replicated 293-partial exclusive scan + offsets.
// ---------------------------------------------------------------------------
__global__ __launch_bounds__(256) void scan23_kernel(
    const int* __restrict__ cnt, const int* __restrict__ part,
    int* __restrict__ off, int* __restrict__ cursor)
{
    __shared__ int sd[256];
    __shared__ int pex[512];
    __shared__ int wt[4];
    const int tid = threadIdx.x, b = blockIdx.x;
    const int lane = tid & 63, wv = tid >> 6;

    int p0 = (2 * tid     < NB) ? part[2 * tid]     : 0;
    int p1 = (2 * tid + 1 < NB) ? part[2 * tid + 1] : 0;
    int ps = p0 + p1;
    sd[tid] = ps; __syncthreads();
    for (int d = 1; d < 256; d <<= 1) {
        int v = (tid >= d) ? sd[tid - d] : 0;
        __syncthreads();
        sd[tid] += v;
        __syncthreads();
    }
    int exc = sd[tid] - ps;
    pex[2 * tid] = exc;
    pex[2 * tid + 1] = exc + p0;
    __syncthreads();

    int i0 = b * 1024 + tid * 4;
    int v[4];
#pragma unroll
    for (int k = 0; k < 4; ++k) { int i = i0 + k; v[k] = (i < ND) ? cnt[i] : 0; }
    int ts = v[0] + v[1] + v[2] + v[3];
    int inc = ts;
#pragma unroll
    for (int d = 1; d < 64; d <<= 1) {
        int u = __shfl_up(inc, d);
        if (lane >= d) inc += u;
    }
    int wexc = inc - ts;
    if (lane == 63) wt[wv] = inc;
    __syncthreads();
    int wbase = 0;
    for (int w = 0; w < wv; ++w) wbase += wt[w];
    int base = pex[b] + wbase + wexc;
    int pre = 0;
#pragma unroll
    for (int k = 0; k < 4; ++k) {
        int i = i0 + k;
        if (i < ND) { off[i] = base + pre; cursor[i] = base + pre; }
        pre += v[k];
    }
}

// ---------------------------------------------------------------------------
// Fill: place src ids in CSR order AND precompute the 8 per-head softmax
// numerators w = exp(leaky_relu(a_s + a_d)) for each edge (f16x8, CSR order).
// ---------------------------------------------------------------------------
__global__ __launch_bounds__(256) void fill_kernel(
    const int* __restrict__ ei00, const int* __restrict__ ei10,
    const int* __restrict__ ei11, const int* __restrict__ ei21,
    const float* __restrict__ as00, const float* __restrict__ ad00,
    const float* __restrict__ as10, const float* __restrict__ ad10,
    const float* __restrict__ as11, const float* __restrict__ ad11,
    const float* __restrict__ as21, const float* __restrict__ ad21,
    int* __restrict__ cursor, int* __restrict__ srcs, _Float16* __restrict__ wgt)
{
    int e = blockIdx.x * 256 + threadIdx.x;
    if (e >= EE) return;
    int src, d, slot;
    const float* asp; const float* adp;
    if (e < E00) {
        src = ei00[e]; d = ei00[E00 + e]; slot = d; asp = as00; adp = ad00;
    } else if (e < E00 + E10) {
        int i = e - E00; src = ei10[i]; d = ei10[E10 + i]; slot = 50000 + d; asp = as10; adp = ad10;
    } else if (e < E00 + E10 + E11) {
        int i = e - E00 - E10; src = ei11[i]; d = ei11[E11 + i]; slot = 100000 + d; asp = as11; adp = ad11;
    } else {
        int i = e - E00 - E10 - E11; src = ei21[i]; d = ei21[E21 + i]; slot = 200000 + d; asp = as21; adp = ad21;
    }
    float4 sa0 = *(const float4*)(asp + (size_t)src * 8);
    float4 sa1 = *(const float4*)(asp + (size_t)src * 8 + 4);
    float4 da0 = *(const float4*)(adp + (size_t)d * 8);
    float4 da1 = *(const float4*)(adp + (size_t)d * 8 + 4);
    float vv[8] = {sa0.x + da0.x, sa0.y + da0.y, sa0.z + da0.z, sa0.w + da0.w,
                   sa1.x + da1.x, sa1.y + da1.y, sa1.z + da1.z, sa1.w + da1.w};
    half8 w;
#pragma unroll
    for (int h = 0; h < 8; ++h) {
        float v = vv[h];
        v = v > 0.f ? v : 0.2f * v;
        w[h] = (_Float16)__expf(v);
    }
    int pos = atomicAdd(&cursor[slot], 1);
    srcs[pos] = src;
    *(half8*)(wgt + (size_t)pos * 8) = w;
}

// ---------------------------------------------------------------------------
// Gather v4: 8 slots per wave, 8 lanes per slot; lane sub covers head sub's
// 16 features (one b128 fp8 load per edge). agg (fp8, relu'ed) written once.
// ---------------------------------------------------------------------------
__global__ __launch_bounds__(256) void gather_kernel(
    const int* __restrict__ cnt, const int* __restrict__ off,
    const int* __restrict__ srcs, const _Float16* __restrict__ wgt,
    const unsigned char* __restrict__ h0, const unsigned char* __restrict__ h1,
    const unsigned char* __restrict__ h2,
    unsigned char* __restrict__ agg)
{
    const int gid = blockIdx.x * 256 + threadIdx.x;
    const int lane = gid & 63;
    const int g8 = lane >> 3, sub = lane & 7;
    const int slot = (gid >> 6) * 8 + g8;           // grid sized so slot < ND
    const unsigned char* hs = (slot < 50000) ? h0 : (slot < 200000) ? h1 : h2;
    const int deg = cnt[slot], st = off[slot];

    int degm = deg;
    degm = max(degm, __shfl_xor(degm, 8));
    degm = max(degm, __shfl_xor(degm, 16));
    degm = max(degm, __shfl_xor(degm, 32));

    float acc[16];
#pragma unroll
    for (int j = 0; j < 16; ++j) acc[j] = 0.f;
    float sw = 0.f;

    int i = 0;
    for (; i + 2 <= degm; i += 2) {
        bool a0 = (i < deg), a1 = (i + 1 < deg);
        int s0 = 0, s1 = 0;
        if (a0) s0 = srcs[st + i];
        if (a1) s1 = srcs[st + i + 1];
        float w0 = 0.f, w1 = 0.f;
        int4 v0 = {0, 0, 0, 0}, v1 = {0, 0, 0, 0};
        if (a0) { w0 = (float)wgt[(size_t)(st + i) * 8 + sub];
                  v0 = *(const int4*)(hs + (size_t)s0 * 128 + sub * 16); }
        if (a1) { w1 = (float)wgt[(size_t)(st + i + 1) * 8 + sub];
                  v1 = *(const int4*)(hs + (size_t)s1 * 128 + sub * 16); }
        const int wa[4] = {v0.x, v0.y, v0.z, v0.w};
        const int wb[4] = {v1.x, v1.y, v1.z, v1.w};
#pragma unroll
        for (int k = 0; k < 4; ++k) {
            floatx2 fa0 = __builtin_amdgcn_cvt_pk_f32_fp8(wa[k], false);
            floatx2 fa1 = __builtin_amdgcn_cvt_pk_f32_fp8(wa[k], true);
            floatx2 fb0 = __builtin_amdgcn_cvt_pk_f32_fp8(wb[k], false);
            floatx2 fb1 = __builtin_amdgcn_cvt_pk_f32_fp8(wb[k], true);
            acc[4 * k + 0] += w0 * fa0.x + w1 * fb0.x;
            acc[4 * k + 1] += w0 * fa0.y + w1 * fb0.y;
            acc[4 * k + 2] += w0 * fa1.x + w1 * fb1.x;
            acc[4 * k + 3] += w0 * fa1.y + w1 * fb1.y;
        }
        sw += w0 + w1;
    }
    if (i < degm) {
        bool a0 = (i < deg);
        int s0 = 0;
        if (a0) s0 = srcs[st + i];
        float w0 = 0.f;
        int4 v0 = {0, 0, 0, 0};
        if (a0) { w0 = (float)wgt[(size_t)(st + i) * 8 + sub];
                  v0 = *(const int4*)(hs + (size_t)s0 * 128 + sub * 16); }
        const int wa[4] = {v0.x, v0.y, v0.z, v0.w};
#pragma unroll
        for (int k = 0; k < 4; ++k) {
            floatx2 fa0 = __builtin_amdgcn_cvt_pk_f32_fp8(wa[k], false);
            floatx2 fa1 = __builtin_amdgcn_cvt_pk_f32_fp8(wa[k], true);
            acc[4 * k + 0] += w0 * fa0.x;
            acc[4 * k + 1] += w0 * fa0.y;
            acc[4 * k + 2] += w0 * fa1.x;
            acc[4 * k + 3] += w0 * fa1.y;
        }
        sw += w0;
    }

    float rr = __builtin_amdgcn_rcpf(sw + 1e-16f);
    int4 o;
    int pk[4];
#pragma unroll
    for (int k = 0; k < 4; ++k) {
        float r0 = fmaxf(acc[4 * k + 0] * rr, 0.f);
        float r1 = fmaxf(acc[4 * k + 1] * rr, 0.f);
        float r2 = fmaxf(acc[4 * k + 2] * rr, 0.f);
        float r3 = fmaxf(acc[4 * k + 3] * rr, 0.f);
        int p = __builtin_amdgcn_cvt_pk_fp8_f32(r0, r1, 0, false);
        p = __builtin_amdgcn_cvt_pk_fp8_f32(r2, r3, p, true);
        pk[k] = p;
    }
    o.x = pk[0]; o.y = pk[1]; o.z = pk[2]; o.w = pk[3];
    *(int4*)(agg + (size_t)slot * 128 + sub * 16) = o;
}

// ---------------------------------------------------------------------------
// Semantic v4 (f-tile-per-block): block b owns f-tile ft = b%9; its 4 waves
// stream over A-tiles (stride 512*4). Per-wave persistent state = 4 B-longs
// (8 VGPRs) + 2 scalars — residency is trivial by construction, killing the
// ~50us floor caused by the compiler demoting 36-long B sets (R7-R15).
// agg is read 9x but is L2/L3-resident (38 MB). Per tile: 4 prefetched
// A-loads + 4 MFMA + (ft<8: 4-elem exp chain | ft==8: 4 adds).
// Last block (done counter) computes softmax+classifier+sigmoid.
// ---------------------------------------------------------------------------
#define SEM_GRPS 512
__global__ __launch_bounds__(256) void semantic_kernel(
    const unsigned char* __restrict__ agg, const unsigned char* __restrict__ kwf8,
    const float* __restrict__ kb, const float* __restrict__ q,
    const float* __restrict__ lb,
    float* __restrict__ cs2, float* __restrict__ score,
    unsigned int* __restrict__ done, float* __restrict__ out)
{
    __shared__ float redv[12];
    const int tid = threadIdx.x;
    const int lane = tid & 63, wv = tid >> 6;
    const int fi = lane & 15, hi = lane >> 4;

    if (tid < 12) redv[tid] = 0.f;
    __syncthreads();

    const int ft  = blockIdx.x % 9;
    const int grp = blockIdx.x / 9;          // 0..SEM_GRPS-1
    const int nw  = SEM_GRPS * 4;            // tile stride

    long b0 = *(const long*)&kwf8[(ft * 16 + fi) * 128 + 0 * 32 + hi * 8];
    long b1 = *(const long*)&kwf8[(ft * 16 + fi) * 128 + 1 * 32 + hi * 8];
    long b2 = *(const long*)&kwf8[(ft * 16 + fi) * 128 + 2 * 32 + hi * 8];
    long b3 = *(const long*)&kwf8[(ft * 16 + fi) * 128 + 3 * 32 + hi * 8];
    const float qv  = (ft < 8) ? q[ft * 16 + fi]  : 0.f;
    const float kbv = (ft < 8) ? kb[ft * 16 + fi] : 0.f;

    float sc[4] = {0.f, 0.f, 0.f, 0.f};
    float cs[4] = {0.f, 0.f, 0.f, 0.f};

    int t = grp * 4 + wv;
    long af[4] = {0, 0, 0, 0};
    if (t < NT_ALL) {
        const unsigned char* rowp = agg + ((size_t)(t * 16 + fi) * 128 + hi * 8);
        af[0] = *(const long*)(rowp);
        af[1] = *(const long*)(rowp + 32);
        af[2] = *(const long*)(rowp + 64);
        af[3] = *(const long*)(rowp + 96);
    }
    while (t < NT_ALL) {
        const int tn = t + nw;
        long afn[4] = {0, 0, 0, 0};
        if (tn < NT_ALL) {
            const unsigned char* rowp = agg + ((size_t)(tn * 16 + fi) * 128 + hi * 8);
            afn[0] = *(const long*)(rowp);
            afn[1] = *(const long*)(rowp + 32);
            afn[2] = *(const long*)(rowp + 64);
            afn[3] = *(const long*)(rowp + 96);
        }
        const int m = (t >= 12500) ? 3 : (t >= 6250) ? 2 : (t >= 3125) ? 1 : 0;
        float4v c = {0.f, 0.f, 0.f, 0.f};
        c = __builtin_amdgcn_mfma_f32_16x16x32_fp8_fp8(af[0], b0, c, 0, 0, 0);
        c = __builtin_amdgcn_mfma_f32_16x16x32_fp8_fp8(af[1], b1, c, 0, 0, 0);
        c = __builtin_amdgcn_mfma_f32_16x16x32_fp8_fp8(af[2], b2, c, 0, 0, 0);
        c = __builtin_amdgcn_mfma_f32_16x16x32_fp8_fp8(af[3], b3, c, 0, 0, 0);
        float tv;
        if (ft < 8) {
            tv = 0.f;
#pragma unroll
            for (int r = 0; r < 4; ++r) {
                float y = c[r] + kbv;
                float e = __expf(2.f * y);
                tv += qv * (1.f - 2.f * __builtin_amdgcn_rcpf(e + 1.f));
            }
        } else {
            tv = c[0] + c[1] + c[2] + c[3];
        }
        if (m == 0)      { sc[0] += tv; }
        else if (m == 1) { sc[1] += tv; }
        else if (m == 2) { sc[2] += tv; }
        else             { sc[3] += tv; }
        t = tn;
        af[0] = afn[0]; af[1] = afn[1]; af[2] = afn[2]; af[3] = afn[3];
    }

    if (ft < 8) {
        // score contribution: full 64-lane reduce per metapath
#pragma unroll
        for (int m = 0; m < 4; ++m) {
            float s = sc[m];
#pragma unroll
            for (int o = 1; o < 64; o <<= 1) s += __shfl_xor(s, o);
            if (lane == 0 && s != 0.f) atomicAdd(&redv[m], s);
        }
    } else {
        // cs: lane fi holds column fi; reduce over hi groups
#pragma unroll
        for (int m = 0; m < 4; ++m) {
            float v = sc[m];
            v += __shfl_xor(v, 16);
            v += __shfl_xor(v, 32);
            if (hi == 0 && fi < 2 && v != 0.f) atomicAdd(&redv[4 + 2 * m + fi], v);
        }
    }
    __syncthreads();
    if (tid < 4 && redv[tid] != 0.f)              atomicAdd(&score[tid], redv[tid]);
    if (tid >= 4 && tid < 12 && redv[tid] != 0.f) atomicAdd(&cs2[tid - 4], redv[tid]);

    // last-block final epilogue
    __syncthreads();
    if (tid == 0) {
        __threadfence();
        unsigned int old = atomicAdd(done, 1u);
        if (old == gridDim.x - 1) {
            __threadfence();
            float s0 = score[0] / (float)N0;
            float s1 = score[1] / (float)N0;
            float s2 = score[2] / (float)N1;
            float s3 = score[3] / (float)N1;
            float m0 = fmaxf(s0, s1);
            float e0 = __expf(s0 - m0), e1 = __expf(s1 - m0);
            float a0 = e0 / (e0 + e1), a1 = e1 / (e0 + e1);
            float m1 = fmaxf(s2, s3);
            float e2 = __expf(s2 - m1), e3 = __expf(s3 - m1);
            float a2 = e2 / (e2 + e3), a3 = e3 / (e2 + e3);
            float z0 = a0 * cs2[0] + a1 * cs2[2] + a2 * cs2[4] + a3 * cs2[6] + lb[0];
            float z1 = a0 * cs2[1] + a1 * cs2[3] + a2 * cs2[5] + a3 * cs2[7] + lb[1];
            out[0] = 1.f / (1.f + __expf(-z0));
            out[1] = 1.f / (1.f + __expf(-z1));
        }
    }
}

extern "C" void kernel_launch(void* const* d_in, const int* in_sizes, int n_in,
                              void* d_out, int out_size, void* d_ws, size_t ws_size,
                              hipStream_t stream)
{
    const float* x0  = (const float*)d_in[0];
    const float* x1  = (const float*)d_in[1];
    const float* x2  = (const float*)d_in[2];
    const int* ei00  = (const int*)d_in[3];
    const int* ei11  = (const int*)d_in[4];
    const int* ei10  = (const int*)d_in[5];
    const int* ei21  = (const int*)d_in[6];
    const float* W0  = (const float*)d_in[7];  const float* b0 = (const float*)d_in[8];
    const float* W1  = (const float*)d_in[9];  const float* b1 = (const float*)d_in[10];
    const float* W2  = (const float*)d_in[11]; const float* b2 = (const float*)d_in[12];
    const float* as00 = (const float*)d_in[13]; const float* ad00 = (const float*)d_in[14];
    const float* as11 = (const float*)d_in[15]; const float* ad11 = (const float*)d_in[16];
    const float* as10 = (const float*)d_in[17]; const float* ad10 = (const float*)d_in[18];
    const float* as21 = (const float*)d_in[19]; const float* ad21 = (const float*)d_in[20];
    const float* kw  = (const float*)d_in[21]; const float* kb  = (const float*)d_in[22];
    const float* q   = (const float*)d_in[23];
    const float* lw  = (const float*)d_in[24]; const float* lb  = (const float*)d_in[25];
    float* out = (float*)d_out;

    char* p = (char*)d_ws;
    auto alloc = [&](size_t bytes) {
        char* r = p;
        p += (bytes + 255) & ~(size_t)255;
        return r;
    };
    unsigned char* h0 = (unsigned char*)alloc((size_t)N0 * 128);   // fp8 [N][128]
    unsigned char* h1 = (unsigned char*)alloc((size_t)N1 * 128);
    unsigned char* h2 = (unsigned char*)alloc((size_t)N2 * 128);
    float* o_as00 = (float*)alloc((size_t)N0 * 32);
    float* o_ad00 = (float*)alloc((size_t)N0 * 32);
    float* o_as11 = (float*)alloc((size_t)N1 * 32);
    float* o_ad11 = (float*)alloc((size_t)N1 * 32);
    float* o_as10 = (float*)alloc((size_t)N1 * 32);   // src of b10 = cell1
    float* o_ad10 = (float*)alloc((size_t)N0 * 32);   // dst of b10 = cell0
    float* o_as21 = (float*)alloc((size_t)N2 * 32);   // src of b21 = cell2
    float* o_ad21 = (float*)alloc((size_t)N1 * 32);   // dst of b21 = cell1
    int* off    = (int*)alloc((size_t)ND * 4);
    int* cursor = (int*)alloc((size_t)ND * 4);
    int* part   = (int*)alloc((size_t)512 * 4);
    int* srcs   = (int*)alloc((size_t)EE * 4);
    _Float16* wgt = (_Float16*)alloc((size_t)EE * 16);             // f16x8 per edge
    unsigned char* agg = (unsigned char*)alloc((size_t)ND * 128);  // fp8 [u00|b10|u11|b21]
    _Float16* wtg0 = (_Float16*)alloc(128 * 64 * 2);
    _Float16* wtg1 = (_Float16*)alloc(128 * 64 * 2);
    _Float16* wtg2 = (_Float16*)alloc(128 * 64 * 2);
    _Float16* adtg0 = (_Float16*)alloc(32 * 64 * 2);
    _Float16* adtg1 = (_Float16*)alloc(32 * 64 * 2);
    _Float16* adtg2 = (_Float16*)alloc(32 * 64 * 2);
    float* bdcg = (float*)alloc(3 * 32 * 4);
    unsigned char* kwf8 = (unsigned char*)alloc(144 * 128);
    // ---- zero region (contiguous) ----
    char* zstart = p;
    int* cnt = (int*)alloc((size_t)ND * 4);
    float* colsum2 = (float*)alloc(8 * 4);
    float* score   = (float*)alloc(4 * 4);
    unsigned int* done = (unsigned int*)alloc(4);
    size_t zbytes = (size_t)(p - zstart);

    (void)hipMemsetAsync(zstart, 0, zbytes, stream);

    // A: prep (+ count)
    PrepT pp0 = {W0, b0, as00, ad00, ad10, nullptr, wtg0, adtg0, bdcg + 0};
    PrepT pp1 = {W1, b1, as11, ad11, as10, ad21,    wtg1, adtg1, bdcg + 32};
    PrepT pp2 = {W2, b2, as21, nullptr, nullptr, nullptr, wtg2, adtg2, bdcg + 64};
    prep_kernel<<<32 + (EE + 255) / 256, 256, 0, stream>>>(
        pp0, pp1, pp2, kw, lw, kwf8, ei00, ei10, ei11, ei21, cnt);

    // B: proj (+ scan1). proj blocks [0,296) cell0, [296,880) cell1, [880,1024) cell2
    PT t0 = {x0, b0, h0,
             o_as00, o_ad00, o_ad10, nullptr,
             wtg0, adtg0, bdcg + 0,
             N0, 3125, 0, 296};
    PT t1 = {x1, b1, h1,
             o_as11, o_ad11, o_as10, o_ad21,
             wtg1, adtg1, bdcg + 32,
             N1, 6250, 296, 584};
    PT t2 = {x2, b2, h2,
             o_as21, nullptr, nullptr, nullptr,
             wtg2, adtg2, bdcg + 64,
             N2, 1563, 880, 144};
    proj_mfma<<<PROJ_BLKS + NB, 256, 0, stream>>>(t0, t1, t2, cnt, part);

    // C: scan2+scan3 fused
    scan23_kernel<<<NB, 256, 0, stream>>>(cnt, part, off, cursor);

    // D: fill (CSR placement + per-edge softmax numerators)
    fill_kernel<<<(EE + 255) / 256, 256, 0, stream>>>(ei00, ei10, ei11, ei21,
        o_as00, o_ad00, o_as10, o_ad10, o_as11, o_ad11, o_as21, o_ad21,
        cursor, srcs, wgt);

    // E: gather v4 (8 slots/wave)
    gather_kernel<<<ND / 32, 256, 0, stream>>>(cnt, off, srcs, wgt, h0, h1, h2, agg);

    // F: semantic v4 (f-tile per block, trivially-resident B) + final epilogue
    semantic_kernel<<<9 * SEM_GRPS, 256, 0, stream>>>(agg, kwf8, kb, q, lb,
                                                      colsum2, score, done, out);
}

// Round 17
// 284.302 us; speedup vs baseline: 1.5157x; 1.5157x over previous
//
#include <hip/hip_runtime.h>
#include <hip/hip_fp16.h>

#define N0 50000
#define N1 100000
#define N2 25000
#define E00 200000
#define E11 200000
#define E10 100000
#define E21 50000
#define EE  550000   // E00+E10+E11+E21 (concatenated edge space)
#define ND  300000   // 50000(u00)+50000(b10)+100000(u11)+100000(b21) dst slots
#define NB  293      // ceil(ND/1024) scan blocks
#define NT_ALL 18750 // ND/16 semantic tiles
#define HID 128
#define INC 64

typedef _Float16 half8 __attribute__((ext_vector_type(8)));
typedef _Float16 half4_t __attribute__((ext_vector_type(4)));
typedef float float4v __attribute__((ext_vector_type(4)));
typedef float floatx2 __attribute__((ext_vector_type(2)));

// ---------------------------------------------------------------------------
// Kernel A: prep (+count fused, independent work co-runs).
//   blocks 0..23  : per node type wtg/adtg/bdc (f16, L2-resident)
//   blocks 24..31 : kwf8 = fp8([k_w|lin_w]^T) for semantic
//   blocks 32..   : count edges into cnt[slot]
// ---------------------------------------------------------------------------
struct PrepT {
    const float* W; const float* bias;
    const float* av0; const float* av1; const float* av2; const float* av3;
    _Float16* wtg; _Float16* adtg; float* bdc;
};

__device__ __forceinline__ void decode_edge(
    int e, const int* ei00, const int* ei10, const int* ei11, const int* ei21,
    int& src, int& slot)
{
    if (e < E00)                    { src = ei00[e];               slot = ei00[E00 + e]; }
    else if (e < E00 + E10)         { int i = e - E00;             src = ei10[i]; slot = 50000  + ei10[E10 + i]; }
    else if (e < E00 + E10 + E11)   { int i = e - E00 - E10;       src = ei11[i]; slot = 100000 + ei11[E11 + i]; }
    else                            { int i = e - E00 - E10 - E11; src = ei21[i]; slot = 200000 + ei21[E21 + i]; }
}

__global__ __launch_bounds__(256) void prep_kernel(
    PrepT p0, PrepT p1, PrepT p2,
    const float* __restrict__ kw, const float* __restrict__ lw,
    unsigned char* __restrict__ kwf8,
    const int* __restrict__ ei00, const int* __restrict__ ei10,
    const int* __restrict__ ei11, const int* __restrict__ ei21,
    int* __restrict__ cnt)
{
    if (blockIdx.x >= 32) {
        int e = (blockIdx.x - 32) * 256 + threadIdx.x;
        if (e >= EE) return;
        int src, slot;
        decode_edge(e, ei00, ei10, ei11, ei21, src, slot);
        atomicAdd(&cnt[slot], 1);
        return;
    }
    if (blockIdx.x >= 24) {
        int base = (blockIdx.x - 24) * 256 + threadIdx.x;
        for (int it = 0; it < 9; ++it) {
            int idx = base + it * 2048;
            int f = idx >> 7, g = idx & 127;
            float v;
            if (f < 128)      v = kw[g * 128 + f];
            else if (f < 130) v = lw[g * 2 + (f - 128)];
            else              v = 0.f;
            int r = __builtin_amdgcn_cvt_pk_fp8_f32(v, 0.f, 0, false);
            kwf8[idx] = (unsigned char)r;
        }
        return;
    }
    PrepT P = (blockIdx.x >= 16) ? p2 : (blockIdx.x >= 8) ? p1 : p0;
    const int lb = blockIdx.x & 7;
    const int t2 = lb * 256 + threadIdx.x;   // 0..2047
    {
        int f = t2 >> 4, g0 = (t2 & 15) * 4;
        half4_t v;
#pragma unroll
        for (int j = 0; j < 4; ++j) v[j] = (_Float16)P.W[(g0 + j) * 128 + f];
        *(half4_t*)&P.wtg[f * 64 + g0] = v;
    }
    {
        int c = t2 >> 6, g = t2 & 63;
        const float* av = (c < 8) ? P.av0 : (c < 16) ? P.av1 : (c < 24) ? P.av2 : P.av3;
        float v = 0.f;
        if (av) {
            int hh = c & 7;
#pragma unroll
            for (int d = 0; d < 16; ++d)
                v += P.W[g * 128 + hh * 16 + d] * av[hh * 16 + d];
        }
        P.adtg[c * 64 + g] = (_Float16)v;
    }
    if (lb == 0 && threadIdx.x < 32) {
        int c = threadIdx.x;
        const float* av = (c < 8) ? P.av0 : (c < 16) ? P.av1 : (c < 24) ? P.av2 : P.av3;
        float v = 0.f;
        if (av) {
            int hh = c & 7;
#pragma unroll
            for (int d = 0; d < 16; ++d)
                v += P.bias[hh * 16 + d] * av[hh * 16 + d];
        }
        P.bdc[c] = v;
    }
}

// ---------------------------------------------------------------------------
// Kernel B: proj_mfma (+scan1 fused). h = x @ W + b (fp8 e4m3) + attn dots.
// B frags loaded once from global prep buffers; __launch_bounds__(256,2).
// ---------------------------------------------------------------------------
struct PT {
    const float* x; const float* bias; unsigned char* h;
    float* ao0; float* ao1; float* ao2; float* ao3;
    const _Float16* wtg; const _Float16* adtg; const float* bdc;
    int N; int ntiles; int bstart; int nblocks;
};

#define HPAD 136  // halves; row stride 272 B (16B-aligned b128 reads)
#define PROJ_BLKS 1024

__global__ __launch_bounds__(256, 2) void proj_mfma(
    PT t0, PT t1, PT t2,
    const int* __restrict__ cnt, int* __restrict__ part)
{
    __shared__ _Float16 ht[4][16][HPAD];   // 17.4 KB: per-wave h tile (f16)
    __shared__ int swt[4];
    const int tid = threadIdx.x;
    const int lane = tid & 63, wv = tid >> 6;
    const int fi = lane & 15, hi = lane >> 4;

    if (blockIdx.x >= PROJ_BLKS) {
        const int b = blockIdx.x - PROJ_BLKS;
        int i0 = b * 1024 + tid * 4;
        int s = 0;
#pragma unroll
        for (int k = 0; k < 4; ++k) { int i = i0 + k; s += (i < ND) ? cnt[i] : 0; }
#pragma unroll
        for (int off = 1; off < 64; off <<= 1) s += __shfl_xor(s, off);
        if ((tid & 63) == 0) swt[tid >> 6] = s;
        __syncthreads();
        if (tid == 0) part[b] = swt[0] + swt[1] + swt[2] + swt[3];
        return;
    }

    PT A = (blockIdx.x >= t2.bstart) ? t2 : (blockIdx.x >= t1.bstart) ? t1 : t0;

    half8 bfr[8][2], bd[2][2];
#pragma unroll
    for (int nt = 0; nt < 8; ++nt)
#pragma unroll
        for (int kb = 0; kb < 2; ++kb)
            bfr[nt][kb] = *(const half8*)&A.wtg[(nt * 16 + fi) * 64 + kb * 32 + hi * 8];
#pragma unroll
    for (int t = 0; t < 2; ++t)
#pragma unroll
        for (int kb = 0; kb < 2; ++kb)
            bd[t][kb] = *(const half8*)&A.adtg[(t * 16 + fi) * 64 + kb * 32 + hi * 8];

    float bvv[8];
#pragma unroll
    for (int nt = 0; nt < 8; ++nt) bvv[nt] = A.bias[nt * 16 + fi];
    const float bdc0 = A.bdc[fi];
    const float bdc1 = A.bdc[16 + fi];

    float* aolo = (fi >= 8) ? A.ao1 : A.ao0;
    float* aohi = (fi >= 8) ? A.ao3 : A.ao2;
    const bool has_hi = (A.ao2 != nullptr) || (A.ao3 != nullptr);

    const int stride = A.nblocks * 4;
    for (int t = (blockIdx.x - A.bstart) * 4 + wv; t < A.ntiles; t += stride) {
        const int base = t * 16;
        int rsrc = base + fi; if (rsrc >= A.N) rsrc = A.N - 1;
        const float* xp = A.x + (size_t)rsrc * 64 + hi * 8;
        float4 u0 = *(const float4*)(xp);
        float4 u1 = *(const float4*)(xp + 4);
        float4 u2 = *(const float4*)(xp + 32);
        float4 u3 = *(const float4*)(xp + 36);
        half8 a0, a1;
        a0[0] = (_Float16)u0.x; a0[1] = (_Float16)u0.y; a0[2] = (_Float16)u0.z; a0[3] = (_Float16)u0.w;
        a0[4] = (_Float16)u1.x; a0[5] = (_Float16)u1.y; a0[6] = (_Float16)u1.z; a0[7] = (_Float16)u1.w;
        a1[0] = (_Float16)u2.x; a1[1] = (_Float16)u2.y; a1[2] = (_Float16)u2.z; a1[3] = (_Float16)u2.w;
        a1[4] = (_Float16)u3.x; a1[5] = (_Float16)u3.y; a1[6] = (_Float16)u3.z; a1[7] = (_Float16)u3.w;

        float4v c[8];
#pragma unroll
        for (int nt = 0; nt < 8; ++nt) {
            float4v z = {0.f, 0.f, 0.f, 0.f};
            z = __builtin_amdgcn_mfma_f32_16x16x32_f16(a0, bfr[nt][0], z, 0, 0, 0);
            z = __builtin_amdgcn_mfma_f32_16x16x32_f16(a1, bfr[nt][1], z, 0, 0, 0);
            c[nt] = z;
        }
        float4v d0 = {0.f, 0.f, 0.f, 0.f};
        d0 = __builtin_amdgcn_mfma_f32_16x16x32_f16(a0, bd[0][0], d0, 0, 0, 0);
        d0 = __builtin_amdgcn_mfma_f32_16x16x32_f16(a1, bd[0][1], d0, 0, 0, 0);
        float4v d1 = {0.f, 0.f, 0.f, 0.f};
        if (has_hi) {
            d1 = __builtin_amdgcn_mfma_f32_16x16x32_f16(a0, bd[1][0], d1, 0, 0, 0);
            d1 = __builtin_amdgcn_mfma_f32_16x16x32_f16(a1, bd[1][1], d1, 0, 0, 0);
        }

#pragma unroll
        for (int nt = 0; nt < 8; ++nt)
#pragma unroll
            for (int r = 0; r < 4; ++r)
                ht[wv][hi * 4 + r][nt * 16 + fi] = (_Float16)(c[nt][r] + bvv[nt]);
#pragma unroll
        for (int i = 0; i < 4; ++i) {
            int row = i * 4 + hi;
            int node = base + row;
            if (node < A.N) {
                half8 v = *(const half8*)&ht[wv][row][fi * 8];
                int pa = __builtin_amdgcn_cvt_pk_fp8_f32((float)v[0], (float)v[1], 0, false);
                pa = __builtin_amdgcn_cvt_pk_fp8_f32((float)v[2], (float)v[3], pa, true);
                int pb = __builtin_amdgcn_cvt_pk_fp8_f32((float)v[4], (float)v[5], 0, false);
                pb = __builtin_amdgcn_cvt_pk_fp8_f32((float)v[6], (float)v[7], pb, true);
                int2 o = {pa, pb};
                *(int2*)(A.h + (size_t)node * 128 + fi * 8) = o;
            }
        }
        if (aolo) {
#pragma unroll
            for (int r = 0; r < 4; ++r) {
                int node = base + hi * 4 + r;
                if (node < A.N) aolo[(size_t)node * 8 + (fi & 7)] = d0[r] + bdc0;
            }
        }
        if (aohi) {
#pragma unroll
            for (int r = 0; r < 4; ++r) {
                int node = base + hi * 4 + r;
                if (node < A.N) aohi[(size_t)node * 8 + (fi & 7)] = d1[r] + bdc1;
            }
        }
    }
}

// ---------------------------------------------------------------------------
// Kernel C: scan23 — replicated 293-partial exclusive scan + offsets.
// ---------------------------------------------------------------------------
__global__ __launch_bounds__(256) void scan23_kernel(
    const int* __restrict__ cnt, const int* __restrict__ part,
    int* __restrict__ off, int* __restrict__ cursor)
{
    __shared__ int sd[256];
    __shared__ int pex[512];
    __shared__ int wt[4];
    const int tid = threadIdx.x, b = blockIdx.x;
    const int lane = tid & 63, wv = tid >> 6;

    int p0 = (2 * tid     < NB) ? part[2 * tid]     : 0;
    int p1 = (2 * tid + 1 < NB) ? part[2 * tid + 1] : 0;
    int ps = p0 + p1;
    sd[tid] = ps; __syncthreads();
    for (int d = 1; d < 256; d <<= 1) {
        int v = (tid >= d) ? sd[tid - d] : 0;
        __syncthreads();
        sd[tid] += v;
        __syncthreads();
    }
    int exc = sd[tid] - ps;
    pex[2 * tid] = exc;
    pex[2 * tid + 1] = exc + p0;
    __syncthreads();

    int i0 = b * 1024 + tid * 4;
    int v[4];
#pragma unroll
    for (int k = 0; k < 4; ++k) { int i = i0 + k; v[k] = (i < ND) ? cnt[i] : 0; }
    int ts = v[0] + v[1] + v[2] + v[3];
    int inc = ts;
#pragma unroll
    for (int d = 1; d < 64; d <<= 1) {
        int u = __shfl_up(inc, d);
        if (lane >= d) inc += u;
    }
    int wexc = inc - ts;
    if (lane == 63) wt[wv] = inc;
    __syncthreads();
    int wbase = 0;
    for (int w = 0; w < wv; ++w) wbase += wt[w];
    int base = pex[b] + wbase + wexc;
    int pre = 0;
#pragma unroll
    for (int k = 0; k < 4; ++k) {
        int i = i0 + k;
        if (i < ND) { off[i] = base + pre; cursor[i] = base + pre; }
        pre += v[k];
    }
}

// ---------------------------------------------------------------------------
// Fill: place src ids in CSR order AND precompute the 8 per-head softmax
// numerators w = exp(leaky_relu(a_s + a_d)) for each edge (f16x8, CSR order).
// ---------------------------------------------------------------------------
__global__ __launch_bounds__(256) void fill_kernel(
    const int* __restrict__ ei00, const int* __restrict__ ei10,
    const int* __restrict__ ei11, const int* __restrict__ ei21,
    const float* __restrict__ as00, const float* __restrict__ ad00,
    const float* __restrict__ as10, const float* __restrict__ ad10,
    const float* __restrict__ as11, const float* __restrict__ ad11,
    const float* __restrict__ as21, const float* __restrict__ ad21,
    int* __restrict__ cursor, int* __restrict__ srcs, _Float16* __restrict__ wgt)
{
    int e = blockIdx.x * 256 + threadIdx.x;
    if (e >= EE) return;
    int src, d, slot;
    const float* asp; const float* adp;
    if (e < E00) {
        src = ei00[e]; d = ei00[E00 + e]; slot = d; asp = as00; adp = ad00;
    } else if (e < E00 + E10) {
        int i = e - E00; src = ei10[i]; d = ei10[E10 + i]; slot = 50000 + d; asp = as10; adp = ad10;
    } else if (e < E00 + E10 + E11) {
        int i = e - E00 - E10; src = ei11[i]; d = ei11[E11 + i]; slot = 100000 + d; asp = as11; adp = ad11;
    } else {
        int i = e - E00 - E10 - E11; src = ei21[i]; d = ei21[E21 + i]; slot = 200000 + d; asp = as21; adp = ad21;
    }
    float4 sa0 = *(const float4*)(asp + (size_t)src * 8);
    float4 sa1 = *(const float4*)(asp + (size_t)src * 8 + 4);
    float4 da0 = *(const float4*)(adp + (size_t)d * 8);
    float4 da1 = *(const float4*)(adp + (size_t)d * 8 + 4);
    float vv[8] = {sa0.x + da0.x, sa0.y + da0.y, sa0.z + da0.z, sa0.w + da0.w,
                   sa1.x + da1.x, sa1.y + da1.y, sa1.z + da1.z, sa1.w + da1.w};
    half8 w;
#pragma unroll
    for (int h = 0; h < 8; ++h) {
        float v = vv[h];
        v = v > 0.f ? v : 0.2f * v;
        w[h] = (_Float16)__expf(v);
    }
    int pos = atomicAdd(&cursor[slot], 1);
    srcs[pos] = src;
    *(half8*)(wgt + (size_t)pos * 8) = w;
}

// ---------------------------------------------------------------------------
// Gather v4: 8 slots per wave, 8 lanes per slot; lane sub covers head sub's
// 16 features (one b128 fp8 load per edge). agg (fp8, relu'ed) written once.
// ---------------------------------------------------------------------------
__global__ __launch_bounds__(256) void gather_kernel(
    const int* __restrict__ cnt, const int* __restrict__ off,
    const int* __restrict__ srcs, const _Float16* __restrict__ wgt,
    const unsigned char* __restrict__ h0, const unsigned char* __restrict__ h1,
    const unsigned char* __restrict__ h2,
    unsigned char* __restrict__ agg)
{
    const int gid = blockIdx.x * 256 + threadIdx.x;
    const int lane = gid & 63;
    const int g8 = lane >> 3, sub = lane & 7;
    const int slot = (gid >> 6) * 8 + g8;           // grid sized so slot < ND
    const unsigned char* hs = (slot < 50000) ? h0 : (slot < 200000) ? h1 : h2;
    const int deg = cnt[slot], st = off[slot];

    int degm = deg;
    degm = max(degm, __shfl_xor(degm, 8));
    degm = max(degm, __shfl_xor(degm, 16));
    degm = max(degm, __shfl_xor(degm, 32));

    float acc[16];
#pragma unroll
    for (int j = 0; j < 16; ++j) acc[j] = 0.f;
    float sw = 0.f;

    int i = 0;
    for (; i + 2 <= degm; i += 2) {
        bool a0 = (i < deg), a1 = (i + 1 < deg);
        int s0 = 0, s1 = 0;
        if (a0) s0 = srcs[st + i];
        if (a1) s1 = srcs[st + i + 1];
        float w0 = 0.f, w1 = 0.f;
        int4 v0 = {0, 0, 0, 0}, v1 = {0, 0, 0, 0};
        if (a0) { w0 = (float)wgt[(size_t)(st + i) * 8 + sub];
                  v0 = *(const int4*)(hs + (size_t)s0 * 128 + sub * 16); }
        if (a1) { w1 = (float)wgt[(size_t)(st + i + 1) * 8 + sub];
                  v1 = *(const int4*)(hs + (size_t)s1 * 128 + sub * 16); }
        const int wa[4] = {v0.x, v0.y, v0.z, v0.w};
        const int wb[4] = {v1.x, v1.y, v1.z, v1.w};
#pragma unroll
        for (int k = 0; k < 4; ++k) {
            floatx2 fa0 = __builtin_amdgcn_cvt_pk_f32_fp8(wa[k], false);
            floatx2 fa1 = __builtin_amdgcn_cvt_pk_f32_fp8(wa[k], true);
            floatx2 fb0 = __builtin_amdgcn_cvt_pk_f32_fp8(wb[k], false);
            floatx2 fb1 = __builtin_amdgcn_cvt_pk_f32_fp8(wb[k], true);
            acc[4 * k + 0] += w0 * fa0.x + w1 * fb0.x;
            acc[4 * k + 1] += w0 * fa0.y + w1 * fb0.y;
            acc[4 * k + 2] += w0 * fa1.x + w1 * fb1.x;
            acc[4 * k + 3] += w0 * fa1.y + w1 * fb1.y;
        }
        sw += w0 + w1;
    }
    if (i < degm) {
        bool a0 = (i < deg);
        int s0 = 0;
        if (a0) s0 = srcs[st + i];
        float w0 = 0.f;
        int4 v0 = {0, 0, 0, 0};
        if (a0) { w0 = (float)wgt[(size_t)(st + i) * 8 + sub];
                  v0 = *(const int4*)(hs + (size_t)s0 * 128 + sub * 16); }
        const int wa[4] = {v0.x, v0.y, v0.z, v0.w};
#pragma unroll
        for (int k = 0; k < 4; ++k) {
            floatx2 fa0 = __builtin_amdgcn_cvt_pk_f32_fp8(wa[k], false);
            floatx2 fa1 = __builtin_amdgcn_cvt_pk_f32_fp8(wa[k], true);
            acc[4 * k + 0] += w0 * fa0.x;
            acc[4 * k + 1] += w0 * fa0.y;
            acc[4 * k + 2] += w0 * fa1.x;
            acc[4 * k + 3] += w0 * fa1.y;
        }
        sw += w0;
    }

    float rr = __builtin_amdgcn_rcpf(sw + 1e-16f);
    int4 o;
    int pk[4];
#pragma unroll
    for (int k = 0; k < 4; ++k) {
        float r0 = fmaxf(acc[4 * k + 0] * rr, 0.f);
        float r1 = fmaxf(acc[4 * k + 1] * rr, 0.f);
        float r2 = fmaxf(acc[4 * k + 2] * rr, 0.f);
        float r3 = fmaxf(acc[4 * k + 3] * rr, 0.f);
        int p = __builtin_amdgcn_cvt_pk_fp8_f32(r0, r1, 0, false);
        p = __builtin_amdgcn_cvt_pk_fp8_f32(r2, r3, p, true);
        pk[k] = p;
    }
    o.x = pk[0]; o.y = pk[1]; o.z = pk[2]; o.w = pk[3];
    *(int4*)(agg + (size_t)slot * 128 + sub * 16) = o;
}

// ---------------------------------------------------------------------------
// Semantic (R12 structure, fp8 MFMA over all 4 metapaths) + fused final
// epilogue. B frags loaded once from global kwf8. __launch_bounds__(256,1):
// removes the 2-waves/EU VGPR cap so the allocator MAY keep the 36 fragment
// longs resident (R12's (256,2) chose VGPR=80 and reloaded B per tile).
// metapath: 3=t>=12500, 2=t>=6250, 1=t>=3125, else 0 (u00,b10,u11,b21).
// ---------------------------------------------------------------------------
__global__ __launch_bounds__(256, 1) void semantic_kernel(
    const unsigned char* __restrict__ agg, const unsigned char* __restrict__ kwf8,
    const float* __restrict__ kb, const float* __restrict__ q,
    const float* __restrict__ lb,
    float* __restrict__ cs2, float* __restrict__ score,
    unsigned int* __restrict__ done, float* __restrict__ out)
{
    __shared__ float redv[12];
    const int tid = threadIdx.x;
    const int lane = tid & 63, wv = tid >> 6;
    const int fi = lane & 15, hi = lane >> 4;

    if (tid < 12) redv[tid] = 0.f;
    __syncthreads();

    long bf[9][4];
#pragma unroll
    for (int ft = 0; ft < 9; ++ft)
#pragma unroll
        for (int kk = 0; kk < 4; ++kk)
            bf[ft][kk] = *(const long*)&kwf8[(ft * 16 + fi) * 128 + kk * 32 + hi * 8];

    float qv[8], kbv[8];
#pragma unroll
    for (int ft = 0; ft < 8; ++ft) {
        qv[ft] = q[ft * 16 + fi];
        kbv[ft] = kb[ft * 16 + fi];
    }

    float sc[4] = {0.f, 0.f, 0.f, 0.f};
    float cs[4] = {0.f, 0.f, 0.f, 0.f};
    const int wid = blockIdx.x * 4 + wv;
    const int nw = gridDim.x * 4;

    long af[4] = {0, 0, 0, 0};
    int t = wid;
    if (t < NT_ALL) {
        const unsigned char* rowp = agg + ((size_t)(t * 16 + fi) * 128 + hi * 8);
        af[0] = *(const long*)(rowp);
        af[1] = *(const long*)(rowp + 32);
        af[2] = *(const long*)(rowp + 64);
        af[3] = *(const long*)(rowp + 96);
    }
    while (t < NT_ALL) {
        const int tn = t + nw;
        long afn[4] = {0, 0, 0, 0};
        if (tn < NT_ALL) {
            const unsigned char* rowp = agg + ((size_t)(tn * 16 + fi) * 128 + hi * 8);
            afn[0] = *(const long*)(rowp);
            afn[1] = *(const long*)(rowp + 32);
            afn[2] = *(const long*)(rowp + 64);
            afn[3] = *(const long*)(rowp + 96);
        }
        const int m = (t >= 12500) ? 3 : (t >= 6250) ? 2 : (t >= 3125) ? 1 : 0;
        float tsc = 0.f, tcs;
#pragma unroll
        for (int ft = 0; ft < 8; ++ft) {
            float4v c = {0.f, 0.f, 0.f, 0.f};
            c = __builtin_amdgcn_mfma_f32_16x16x32_fp8_fp8(af[0], bf[ft][0], c, 0, 0, 0);
            c = __builtin_amdgcn_mfma_f32_16x16x32_fp8_fp8(af[1], bf[ft][1], c, 0, 0, 0);
            c = __builtin_amdgcn_mfma_f32_16x16x32_fp8_fp8(af[2], bf[ft][2], c, 0, 0, 0);
            c = __builtin_amdgcn_mfma_f32_16x16x32_fp8_fp8(af[3], bf[ft][3], c, 0, 0, 0);
#pragma unroll
            for (int r = 0; r < 4; ++r) {
                float y = c[r] + kbv[ft];
                float e = __expf(2.f * y);
                tsc += qv[ft] * (1.f - 2.f * __builtin_amdgcn_rcpf(e + 1.f));
            }
        }
        {
            float4v c = {0.f, 0.f, 0.f, 0.f};
            c = __builtin_amdgcn_mfma_f32_16x16x32_fp8_fp8(af[0], bf[8][0], c, 0, 0, 0);
            c = __builtin_amdgcn_mfma_f32_16x16x32_fp8_fp8(af[1], bf[8][1], c, 0, 0, 0);
            c = __builtin_amdgcn_mfma_f32_16x16x32_fp8_fp8(af[2], bf[8][2], c, 0, 0, 0);
            c = __builtin_amdgcn_mfma_f32_16x16x32_fp8_fp8(af[3], bf[8][3], c, 0, 0, 0);
            tcs = c[0] + c[1] + c[2] + c[3];
        }
        if (m == 0)      { sc[0] += tsc; cs[0] += tcs; }
        else if (m == 1) { sc[1] += tsc; cs[1] += tcs; }
        else if (m == 2) { sc[2] += tsc; cs[2] += tcs; }
        else             { sc[3] += tsc; cs[3] += tcs; }
        t = tn;
        af[0] = afn[0]; af[1] = afn[1]; af[2] = afn[2]; af[3] = afn[3];
    }

#pragma unroll
    for (int m = 0; m < 4; ++m) {
        float s = sc[m];
#pragma unroll
        for (int off = 1; off < 64; off <<= 1) s += __shfl_xor(s, off);
        if (lane == 0 && s != 0.f) atomicAdd(&redv[m], s);
        float v = cs[m];
        v += __shfl_xor(v, 16);
        v += __shfl_xor(v, 32);
        if (hi == 0 && fi < 2 && v != 0.f) atomicAdd(&redv[4 + 2 * m + fi], v);
    }
    __syncthreads();
    if (tid < 4)              atomicAdd(&score[tid], redv[tid]);
    if (tid >= 4 && tid < 12) atomicAdd(&cs2[tid - 4], redv[tid]);

    // last-block final epilogue
    __syncthreads();
    if (tid == 0) {
        __threadfence();
        unsigned int old = atomicAdd(done, 1u);
        if (old == gridDim.x - 1) {
            __threadfence();
            float s0 = score[0] / (float)N0;
            float s1 = score[1] / (float)N0;
            float s2 = score[2] / (float)N1;
            float s3 = score[3] / (float)N1;
            float m0 = fmaxf(s0, s1);
            float e0 = __expf(s0 - m0), e1 = __expf(s1 - m0);
            float a0 = e0 / (e0 + e1), a1 = e1 / (e0 + e1);
            float m1 = fmaxf(s2, s3);
            float e2 = __expf(s2 - m1), e3 = __expf(s3 - m1);
            float a2 = e2 / (e2 + e3), a3 = e3 / (e2 + e3);
            float z0 = a0 * cs2[0] + a1 * cs2[2] + a2 * cs2[4] + a3 * cs2[6] + lb[0];
            float z1 = a0 * cs2[1] + a1 * cs2[3] + a2 * cs2[5] + a3 * cs2[7] + lb[1];
            out[0] = 1.f / (1.f + __expf(-z0));
            out[1] = 1.f / (1.f + __expf(-z1));
        }
    }
}

extern "C" void kernel_launch(void* const* d_in, const int* in_sizes, int n_in,
                              void* d_out, int out_size, void* d_ws, size_t ws_size,
                              hipStream_t stream)
{
    const float* x0  = (const float*)d_in[0];
    const float* x1  = (const float*)d_in[1];
    const float* x2  = (const float*)d_in[2];
    const int* ei00  = (const int*)d_in[3];
    const int* ei11  = (const int*)d_in[4];
    const int* ei10  = (const int*)d_in[5];
    const int* ei21  = (const int*)d_in[6];
    const float* W0  = (const float*)d_in[7];  const float* b0 = (const float*)d_in[8];
    const float* W1  = (const float*)d_in[9];  const float* b1 = (const float*)d_in[10];
    const float* W2  = (const float*)d_in[11]; const float* b2 = (const float*)d_in[12];
    const float* as00 = (const float*)d_in[13]; const float* ad00 = (const float*)d_in[14];
    const float* as11 = (const float*)d_in[15]; const float* ad11 = (const float*)d_in[16];
    const float* as10 = (const float*)d_in[17]; const float* ad10 = (const float*)d_in[18];
    const float* as21 = (const float*)d_in[19]; const float* ad21 = (const float*)d_in[20];
    const float* kw  = (const float*)d_in[21]; const float* kb  = (const float*)d_in[22];
    const float* q   = (const float*)d_in[23];
    const float* lw  = (const float*)d_in[24]; const float* lb  = (const float*)d_in[25];
    float* out = (float*)d_out;

    char* p = (char*)d_ws;
    auto alloc = [&](size_t bytes) {
        char* r = p;
        p += (bytes + 255) & ~(size_t)255;
        return r;
    };
    unsigned char* h0 = (unsigned char*)alloc((size_t)N0 * 128);   // fp8 [N][128]
    unsigned char* h1 = (unsigned char*)alloc((size_t)N1 * 128);
    unsigned char* h2 = (unsigned char*)alloc((size_t)N2 * 128);
    float* o_as00 = (float*)alloc((size_t)N0 * 32);
    float* o_ad00 = (float*)alloc((size_t)N0 * 32);
    float* o_as11 = (float*)alloc((size_t)N1 * 32);
    float* o_ad11 = (float*)alloc((size_t)N1 * 32);
    float* o_as10 = (float*)alloc((size_t)N1 * 32);   // src of b10 = cell1
    float* o_ad10 = (float*)alloc((size_t)N0 * 32);   // dst of b10 = cell0
    float* o_as21 = (float*)alloc((size_t)N2 * 32);   // src of b21 = cell2
    float* o_ad21 = (float*)alloc((size_t)N1 * 32);   // dst of b21 = cell1
    int* off    = (int*)alloc((size_t)ND * 4);
    int* cursor = (int*)alloc((size_t)ND * 4);
    int* part   = (int*)alloc((size_t)512 * 4);
    int* srcs   = (int*)alloc((size_t)EE * 4);
    _Float16* wgt = (_Float16*)alloc((size_t)EE * 16);             // f16x8 per edge
    unsigned char* agg = (unsigned char*)alloc((size_t)ND * 128);  // fp8 [u00|b10|u11|b21]
    _Float16* wtg0 = (_Float16*)alloc(128 * 64 * 2);
    _Float16* wtg1 = (_Float16*)alloc(128 * 64 * 2);
    _Float16* wtg2 = (_Float16*)alloc(128 * 64 * 2);
    _Float16* adtg0 = (_Float16*)alloc(32 * 64 * 2);
    _Float16* adtg1 = (_Float16*)alloc(32 * 64 * 2);
    _Float16* adtg2 = (_Float16*)alloc(32 * 64 * 2);
    float* bdcg = (float*)alloc(3 * 32 * 4);
    unsigned char* kwf8 = (unsigned char*)alloc(144 * 128);
    // ---- zero region (contiguous) ----
    char* zstart = p;
    int* cnt = (int*)alloc((size_t)ND * 4);
    float* colsum2 = (float*)alloc(8 * 4);
    float* score   = (float*)alloc(4 * 4);
    unsigned int* done = (unsigned int*)alloc(4);
    size_t zbytes = (size_t)(p - zstart);

    (void)hipMemsetAsync(zstart, 0, zbytes, stream);

    // A: prep (+ count)
    PrepT pp0 = {W0, b0, as00, ad00, ad10, nullptr, wtg0, adtg0, bdcg + 0};
    PrepT pp1 = {W1, b1, as11, ad11, as10, ad21,    wtg1, adtg1, bdcg + 32};
    PrepT pp2 = {W2, b2, as21, nullptr, nullptr, nullptr, wtg2, adtg2, bdcg + 64};
    prep_kernel<<<32 + (EE + 255) / 256, 256, 0, stream>>>(
        pp0, pp1, pp2, kw, lw, kwf8, ei00, ei10, ei11, ei21, cnt);

    // B: proj (+ scan1). proj blocks [0,296) cell0, [296,880) cell1, [880,1024) cell2
    PT t0 = {x0, b0, h0,
             o_as00, o_ad00, o_ad10, nullptr,
             wtg0, adtg0, bdcg + 0,
             N0, 3125, 0, 296};
    PT t1 = {x1, b1, h1,
             o_as11, o_ad11, o_as10, o_ad21,
             wtg1, adtg1, bdcg + 32,
             N1, 6250, 296, 584};
    PT t2 = {x2, b2, h2,
             o_as21, nullptr, nullptr, nullptr,
             wtg2, adtg2, bdcg + 64,
             N2, 1563, 880, 144};
    proj_mfma<<<PROJ_BLKS + NB, 256, 0, stream>>>(t0, t1, t2, cnt, part);

    // C: scan2+scan3 fused
    scan23_kernel<<<NB, 256, 0, stream>>>(cnt, part, off, cursor);

    // D: fill (CSR placement + per-edge softmax numerators)
    fill_kernel<<<(EE + 255) / 256, 256, 0, stream>>>(ei00, ei10, ei11, ei21,
        o_as00, o_ad00, o_as10, o_ad10, o_as11, o_ad11, o_as21, o_ad21,
        cursor, srcs, wgt);

    // E: gather v4 (8 slots/wave)
    gather_kernel<<<ND / 32, 256, 0, stream>>>(cnt, off, srcs, wgt, h0, h1, h2, agg);

    // F: semantic (+ fused final epilogue), R12 grid
    semantic_kernel<<<1024, 256, 0, stream>>>(agg, kwf8, kb, q, lb,
                                              colsum2, score, done, out);
}